// Round 3
// baseline (505.327 us; speedup 1.0000x reference)
//
#include <hip/hip_runtime.h>
#include <math.h>

#define VOCAB 50000
#define DW 300
#define DH 50
#define G4 200
#define BATCH 1024
#define TMAX 200
#define OUTC 4

// workspace layout (floats):
//   emb_proj : VOCAB*G4            = 10,000,000   (gate-permuted columns)
//   w_T      : DW*G4               =     60,000   (w_ih transposed)
//   w2       : DH*4*52             =     10,400   (w_hh gate-major, rows padded to 52)

// ---------------------------------------------------------------------------
__global__ __launch_bounds__(256) void prep_kernel(
    const float* __restrict__ w_ih, const float* __restrict__ w_hh,
    float* __restrict__ w_T, float* __restrict__ w2)
{
    int i = blockIdx.x * 256 + threadIdx.x;
    if (i < G4 * DW) {                        // transpose w_ih [200][300] -> [300][200]
        int u = i / DW, k = i % DW;
        w_T[k * G4 + u] = w_ih[i];
    }
    int j = i - G4 * DW;
    if (j >= 0 && j < DH * 208) {             // w2[l][g][0..51] = w_hh[g*50+l][k] (pad 0)
        int l = j / 208, r = j % 208;
        int g = r / 52, k = r % 52;
        w2[j] = (k < DH) ? w_hh[(g * DH + l) * DH + k] : 0.f;
    }
}

// ---------------------------------------------------------------------------
// proj: emb_proj[v][(u%50)*4+u/50] = emb[v]·w_ih[u] + b_ih[u] + b_hh[u]
// No LDS: emb reads are 25-lane broadcast (free), each emb element touched
// once per block. Hand ping-pong pipeline: iteration k's 16 loads issue
// before iteration k-1's 256 FMAs, hiding L2 latency.
__device__ __forceinline__ float getc(const float4& v, int kc) {
    return kc == 0 ? v.x : kc == 1 ? v.y : kc == 2 ? v.z : v.w;
}

__device__ __forceinline__ void loade(const float* eb, int kk, float4 (&e)[8]) {
#pragma unroll
    for (int m = 0; m < 8; m++)
        e[m] = *(const float4*)(eb + m * DW + kk * 4);
}
__device__ __forceinline__ void loadw(const float* wb, int kk,
                                      float4 (&wa)[4], float4 (&wb4)[4]) {
#pragma unroll
    for (int j = 0; j < 4; j++) {
        wa[j]  = *(const float4*)(wb + (kk * 4 + j) * G4);
        wb4[j] = *(const float4*)(wb + (kk * 4 + j) * G4 + 4);
    }
}
__device__ __forceinline__ void comp8(const float4 (&e)[8],
                                      const float4 (&wa)[4], const float4 (&wb4)[4],
                                      float (&acc)[8][8]) {
#pragma unroll
    for (int j = 0; j < 4; j++) {
#pragma unroll
        for (int m = 0; m < 8; m++) {
            float ev = getc(e[m], j);
            acc[m][0] = fmaf(ev, wa[j].x,  acc[m][0]);
            acc[m][1] = fmaf(ev, wa[j].y,  acc[m][1]);
            acc[m][2] = fmaf(ev, wa[j].z,  acc[m][2]);
            acc[m][3] = fmaf(ev, wa[j].w,  acc[m][3]);
            acc[m][4] = fmaf(ev, wb4[j].x, acc[m][4]);
            acc[m][5] = fmaf(ev, wb4[j].y, acc[m][5]);
            acc[m][6] = fmaf(ev, wb4[j].z, acc[m][6]);
            acc[m][7] = fmaf(ev, wb4[j].w, acc[m][7]);
        }
    }
}

__global__ __launch_bounds__(256, 2) void proj_kernel(
    const float* __restrict__ emb, const float* __restrict__ w_T,
    const float* __restrict__ b_ih, const float* __restrict__ b_hh,
    float* __restrict__ emb_proj)
{
    const int tid = threadIdx.x;
    const int tt  = (tid < 250) ? tid : 249;   // 250-255 duplicate 249 (benign)
    const int m_idx = tt / 25, n_idx = tt % 25;
    const int r0 = blockIdx.x * 80 + m_idx * 8;

    const float* eb = emb + (size_t)r0 * DW;
    const float* wb = w_T + n_idx * 8;

    float acc[8][8];
#pragma unroll
    for (int m = 0; m < 8; m++)
#pragma unroll
        for (int c = 0; c < 8; c++) acc[m][c] = 0.f;

    float4 eC[8], eN[8], wCa[4], wCb[4], wNa[4], wNb[4];
    loade(eb, 0, eC); loadw(wb, 0, wCa, wCb);

    for (int k4 = 0; k4 < 74; k4 += 2) {
        loade(eb, k4 + 1, eN); loadw(wb, k4 + 1, wNa, wNb);
        comp8(eC, wCa, wCb, acc);
        loade(eb, k4 + 2, eC); loadw(wb, k4 + 2, wCa, wCb);
        comp8(eN, wNa, wNb, acc);
    }
    comp8(eC, wCa, wCb, acc);   // k4 = 74

#pragma unroll
    for (int c = 0; c < 8; c++) {
        int u = n_idx * 8 + c;
        float bias = b_ih[u] + b_hh[u];
        int u2 = (u % DH) * 4 + (u / DH);       // gate-permuted column
#pragma unroll
        for (int m = 0; m < 8; m++)
            emb_proj[(size_t)(r0 + m) * G4 + u2] = acc[m][c] + bias;
    }
}

// ---------------------------------------------------------------------------
// lstm: one 64-lane wave per batch element. Lane l owns unit l (4 gate rows
// of w_hh in 208 VGPRs, loaded as aligned float4 from padded w2). h is
// broadcast lane->all via v_readlane (no LDS in the loop). Prefetch is a
// true depth-2 ping-pong (no register moves -> no early vmcnt wait).
// Steps run to even count with branchless freeze (exact mask semantics).
__device__ __forceinline__ float tanh_f(float x) {
    float e2 = __expf(fminf(2.f * x, 60.f));
    return (e2 - 1.f) / (e2 + 1.f);
}

__device__ __forceinline__ void lstm_step(float4 cur, int tt, int len,
                                          const float4 (&w4)[4][13],
                                          float& hn, float& c) {
    float gi = cur.x, gf = cur.y, gc = cur.z, go = cur.w;
#pragma unroll
    for (int k = 0; k < DH; k++) {
        float hk = __uint_as_float(
            __builtin_amdgcn_readlane(__float_as_uint(hn), k));
        const int k4 = k >> 2, kc = k & 3;
        gi = fmaf(hk, getc(w4[0][k4], kc), gi);
        gf = fmaf(hk, getc(w4[1][k4], kc), gf);
        gc = fmaf(hk, getc(w4[2][k4], kc), gc);
        go = fmaf(hk, getc(w4[3][k4], kc), go);
    }
    float si = 1.f / (1.f + __expf(-gi));
    float sf = 1.f / (1.f + __expf(-gf));
    float so = 1.f / (1.f + __expf(-go));
    float cn = fmaf(sf, c, si * tanh_f(gc));
    float hh = so * tanh_f(cn);
    bool act = tt < len;          // wave-uniform
    c  = act ? cn : c;
    hn = act ? hh : hn;
}

__global__ __launch_bounds__(64, 1) void lstm_kernel(
    const int* __restrict__ x, const int* __restrict__ lengs,
    const float* __restrict__ emb_proj, const float* __restrict__ w2,
    const float* __restrict__ w_out, const float* __restrict__ b_out,
    float* __restrict__ out)
{
    __shared__ float h_fin[DH];
    __shared__ float red[OUTC];
    __shared__ int x_s[TMAX];

    const int l  = threadIdx.x;
    const int b  = blockIdx.x;
    const int ll = (l < DH) ? l : DH - 1;
    const int len = lengs[b];

    for (int i = l; i < TMAX; i += 64) x_s[i] = x[b * TMAX + i];

    float4 w4[4][13];
    {
        const float4* wp = (const float4*)w2 + ll * 52;
#pragma unroll
        for (int g = 0; g < 4; g++)
#pragma unroll
            for (int k4 = 0; k4 < 13; k4++) w4[g][k4] = wp[g * 13 + k4];
    }
    __syncthreads();

    const float* ep = emb_proj + 4 * ll;
    float hn = 0.f, c = 0.f;
    float4 pA = *(const float4*)(ep + (size_t)x_s[0] * G4);
    float4 pB = *(const float4*)(ep + (size_t)x_s[1] * G4);

    const int T2 = (len + 1) & ~1;
    for (int t = 0; t < T2; t += 2) {
        int n2 = (t + 2 < TMAX) ? t + 2 : TMAX - 1;
        int n3 = (t + 3 < TMAX) ? t + 3 : TMAX - 1;
        int tok2 = x_s[n2], tok3 = x_s[n3];

        float4 curA = pA;
        pA = *(const float4*)(ep + (size_t)tok2 * G4);
        lstm_step(curA, t, len, w4, hn, c);

        float4 curB = pB;
        pB = *(const float4*)(ep + (size_t)tok3 * G4);
        lstm_step(curB, t + 1, len, w4, hn, c);
    }

    if (l < DH) h_fin[l] = hn;
    __syncthreads();

    if (l < OUTC) {
        float lg = b_out[l];
        const float* wo = w_out + l * DH;
#pragma unroll
        for (int k = 0; k < DH; k++) lg = fmaf(h_fin[k], wo[k], lg);
        red[l] = lg;
    }
    __syncthreads();
    if (l < OUTC) {
        float m = fmaxf(fmaxf(red[0], red[1]), fmaxf(red[2], red[3]));
        float s = 0.f;
#pragma unroll
        for (int j = 0; j < OUTC; j++) s += __expf(red[j] - m);
        out[b * OUTC + l] = __expf(red[l] - m) / s;
    }
}

// ---------------------------------------------------------------------------
extern "C" void kernel_launch(void* const* d_in, const int* in_sizes, int n_in,
                              void* d_out, int out_size, void* d_ws, size_t ws_size,
                              hipStream_t stream) {
    const int*   x     = (const int*)d_in[0];
    const int*   lengs = (const int*)d_in[1];
    const float* emb   = (const float*)d_in[2];
    const float* w_ih  = (const float*)d_in[3];
    const float* w_hh  = (const float*)d_in[4];
    const float* b_ih  = (const float*)d_in[5];
    const float* b_hh  = (const float*)d_in[6];
    const float* w_out = (const float*)d_in[7];
    const float* b_out = (const float*)d_in[8];
    float* out = (float*)d_out;

    float* emb_proj = (float*)d_ws;
    float* w_T      = emb_proj + (size_t)VOCAB * G4;
    float* w2       = w_T + (size_t)DW * G4;

    hipLaunchKernelGGL(prep_kernel, dim3((G4 * DW + DH * 208 + 255) / 256),
                       dim3(256), 0, stream, w_ih, w_hh, w_T, w2);
    hipLaunchKernelGGL(proj_kernel, dim3(VOCAB / 80), dim3(256), 0, stream,
                       emb, w_T, b_ih, b_hh, emb_proj);
    hipLaunchKernelGGL(lstm_kernel, dim3(BATCH), dim3(64), 0, stream,
                       x, lengs, emb_proj, w2, w_out, b_out, out);
}

// Round 4
// 389.653 us; speedup vs baseline: 1.2969x; 1.2969x over previous
//
#include <hip/hip_runtime.h>
#include <math.h>

#define VOCAB 50000
#define DW 300
#define DH 50
#define G4 200
#define BATCH 1024
#define TMAX 200
#define OUTC 4

// workspace layout (floats):
//   emb_proj : VOCAB*G4  = 10,000,000   (gate-permuted columns)
//   w_T      : DW*G4     =     60,000   (w_ih transposed)
//   w2       : DH*4*52   =     10,400   (w_hh gate-major, rows padded to 52)

// ---------------------------------------------------------------------------
__global__ __launch_bounds__(256) void prep_kernel(
    const float* __restrict__ w_ih, const float* __restrict__ w_hh,
    float* __restrict__ w_T, float* __restrict__ w2)
{
    int i = blockIdx.x * 256 + threadIdx.x;
    if (i < G4 * DW) {                        // transpose w_ih [200][300] -> [300][200]
        int u = i / DW, k = i % DW;
        w_T[k * G4 + u] = w_ih[i];
    }
    int j = i - G4 * DW;
    if (j >= 0 && j < DH * 208) {             // w2[l][g][0..51] = w_hh[g*50+l][k] (pad 0)
        int l = j / 208, r = j % 208;
        int g = r / 52, k = r % 52;
        w2[j] = (k < DH) ? w_hh[(g * DH + l) * DH + k] : 0.f;
    }
}

// ---------------------------------------------------------------------------
// proj: emb_proj[v][(u%50)*4+u/50] = emb[v]·w_ih[u] + b_ih[u] + b_hh[u]
// No LDS: emb reads are lane-broadcast, w_T coalesced from L2. Ping-pong
// pipeline hides L2 latency. amdgpu_waves_per_eu(2,2): VGPR budget 256 so the
// 212-reg working set (64 acc + 128 pipeline) does NOT spill (R3 bug: default
// 4-waves/EU target = 128 budget -> acc spilled to scratch).
__device__ __forceinline__ float getc(const float4& v, int kc) {
    return kc == 0 ? v.x : kc == 1 ? v.y : kc == 2 ? v.z : v.w;
}

__device__ __forceinline__ void loade(const float* eb, int kk, float4 (&e)[8]) {
#pragma unroll
    for (int m = 0; m < 8; m++)
        e[m] = *(const float4*)(eb + m * DW + kk * 4);
}
__device__ __forceinline__ void loadw(const float* wb, int kk,
                                      float4 (&wa)[4], float4 (&wb4)[4]) {
#pragma unroll
    for (int j = 0; j < 4; j++) {
        wa[j]  = *(const float4*)(wb + (kk * 4 + j) * G4);
        wb4[j] = *(const float4*)(wb + (kk * 4 + j) * G4 + 4);
    }
}
__device__ __forceinline__ void comp8(const float4 (&e)[8],
                                      const float4 (&wa)[4], const float4 (&wb4)[4],
                                      float (&acc)[8][8]) {
#pragma unroll
    for (int j = 0; j < 4; j++) {
#pragma unroll
        for (int m = 0; m < 8; m++) {
            float ev = getc(e[m], j);
            acc[m][0] = fmaf(ev, wa[j].x,  acc[m][0]);
            acc[m][1] = fmaf(ev, wa[j].y,  acc[m][1]);
            acc[m][2] = fmaf(ev, wa[j].z,  acc[m][2]);
            acc[m][3] = fmaf(ev, wa[j].w,  acc[m][3]);
            acc[m][4] = fmaf(ev, wb4[j].x, acc[m][4]);
            acc[m][5] = fmaf(ev, wb4[j].y, acc[m][5]);
            acc[m][6] = fmaf(ev, wb4[j].z, acc[m][6]);
            acc[m][7] = fmaf(ev, wb4[j].w, acc[m][7]);
        }
    }
}

__global__ __launch_bounds__(256)
__attribute__((amdgpu_waves_per_eu(2, 2)))
void proj_kernel(
    const float* __restrict__ emb, const float* __restrict__ w_T,
    const float* __restrict__ b_ih, const float* __restrict__ b_hh,
    float* __restrict__ emb_proj)
{
    const int tid = threadIdx.x;
    const int tt  = (tid < 250) ? tid : 249;   // 250-255 duplicate 249 (benign)
    const int m_idx = tt / 25, n_idx = tt % 25;
    const int r0 = blockIdx.x * 80 + m_idx * 8;

    const float* eb = emb + (size_t)r0 * DW;
    const float* wb = w_T + n_idx * 8;

    float acc[8][8];
#pragma unroll
    for (int m = 0; m < 8; m++)
#pragma unroll
        for (int c = 0; c < 8; c++) acc[m][c] = 0.f;

    float4 eC[8], eN[8], wCa[4], wCb[4], wNa[4], wNb[4];
    loade(eb, 0, eC); loadw(wb, 0, wCa, wCb);

    for (int k4 = 0; k4 < 74; k4 += 2) {
        loade(eb, k4 + 1, eN); loadw(wb, k4 + 1, wNa, wNb);
        comp8(eC, wCa, wCb, acc);
        loade(eb, k4 + 2, eC); loadw(wb, k4 + 2, wCa, wCb);
        comp8(eN, wNa, wNb, acc);
    }
    comp8(eC, wCa, wCb, acc);   // k4 = 74

#pragma unroll
    for (int c = 0; c < 8; c++) {
        int u = n_idx * 8 + c;
        float bias = b_ih[u] + b_hh[u];
        int u2 = (u % DH) * 4 + (u / DH);       // gate-permuted column
#pragma unroll
        for (int m = 0; m < 8; m++)
            emb_proj[(size_t)(r0 + m) * G4 + u2] = acc[m][c] + bias;
    }
}

// ---------------------------------------------------------------------------
// lstm: one 64-lane wave per batch element (1024 waves = 1/SIMD, so occupancy
// >1 wave/EU is physically useless). amdgpu_waves_per_eu(1,1) pins the
// compiler's occupancy target so the 208-float w_hh register file actually
// allocates (R2/R3 bug: scheduler targeted 4 waves/EU -> spilled W, reloaded
// from memory every step). h broadcast via v_readlane; depth-2 ping-pong
// prefetch with no register moves; branchless freeze == exact mask semantics.
__device__ __forceinline__ float tanh_f(float x) {
    float e2 = __expf(fminf(2.f * x, 60.f));
    return (e2 - 1.f) / (e2 + 1.f);
}

__device__ __forceinline__ void lstm_step(float4 cur, int tt, int len,
                                          const float4 (&w4)[4][13],
                                          float& hn, float& c) {
    float gi = cur.x, gf = cur.y, gc = cur.z, go = cur.w;
#pragma unroll
    for (int k = 0; k < DH; k++) {
        float hk = __uint_as_float(
            __builtin_amdgcn_readlane(__float_as_uint(hn), k));
        const int k4 = k >> 2, kc = k & 3;
        gi = fmaf(hk, getc(w4[0][k4], kc), gi);
        gf = fmaf(hk, getc(w4[1][k4], kc), gf);
        gc = fmaf(hk, getc(w4[2][k4], kc), gc);
        go = fmaf(hk, getc(w4[3][k4], kc), go);
    }
    float si = 1.f / (1.f + __expf(-gi));
    float sf = 1.f / (1.f + __expf(-gf));
    float so = 1.f / (1.f + __expf(-go));
    float cn = fmaf(sf, c, si * tanh_f(gc));
    float hh = so * tanh_f(cn);
    bool act = tt < len;          // wave-uniform
    c  = act ? cn : c;
    hn = act ? hh : hn;
}

__global__ __launch_bounds__(64)
__attribute__((amdgpu_waves_per_eu(1, 1)))
void lstm_kernel(
    const int* __restrict__ x, const int* __restrict__ lengs,
    const float* __restrict__ emb_proj, const float* __restrict__ w2,
    const float* __restrict__ w_out, const float* __restrict__ b_out,
    float* __restrict__ out)
{
    __shared__ float h_fin[DH];
    __shared__ float red[OUTC];
    __shared__ int x_s[TMAX];

    const int l  = threadIdx.x;
    const int b  = blockIdx.x;
    const int ll = (l < DH) ? l : DH - 1;
    const int len = lengs[b];

    // W first: 4 gate rows of unit ll -> 52 aligned float4 (208 VGPRs)
    float4 w4[4][13];
    {
        const float4* wp = (const float4*)w2 + ll * 52;
#pragma unroll
        for (int g = 0; g < 4; g++)
#pragma unroll
            for (int k4 = 0; k4 < 13; k4++) w4[g][k4] = wp[g * 13 + k4];
    }

    for (int i = l; i < TMAX; i += 64) x_s[i] = x[b * TMAX + i];
    __syncthreads();

    const float* ep = emb_proj + 4 * ll;
    float hn = 0.f, c = 0.f;
    float4 pA = *(const float4*)(ep + (size_t)x_s[0] * G4);
    float4 pB = *(const float4*)(ep + (size_t)x_s[1] * G4);

    const int T2 = (len + 1) & ~1;
    for (int t = 0; t < T2; t += 2) {
        int n2 = (t + 2 < TMAX) ? t + 2 : TMAX - 1;
        int n3 = (t + 3 < TMAX) ? t + 3 : TMAX - 1;
        int tok2 = x_s[n2], tok3 = x_s[n3];

        float4 curA = pA;
        pA = *(const float4*)(ep + (size_t)tok2 * G4);
        lstm_step(curA, t, len, w4, hn, c);

        float4 curB = pB;
        pB = *(const float4*)(ep + (size_t)tok3 * G4);
        lstm_step(curB, t + 1, len, w4, hn, c);
    }

    if (l < DH) h_fin[l] = hn;
    __syncthreads();

    if (l < OUTC) {
        float lg = b_out[l];
        const float* wo = w_out + l * DH;
#pragma unroll
        for (int k = 0; k < DH; k++) lg = fmaf(h_fin[k], wo[k], lg);
        red[l] = lg;
    }
    __syncthreads();
    if (l < OUTC) {
        float m = fmaxf(fmaxf(red[0], red[1]), fmaxf(red[2], red[3]));
        float s = 0.f;
#pragma unroll
        for (int j = 0; j < OUTC; j++) s += __expf(red[j] - m);
        out[b * OUTC + l] = __expf(red[l] - m) / s;
    }
}

// ---------------------------------------------------------------------------
extern "C" void kernel_launch(void* const* d_in, const int* in_sizes, int n_in,
                              void* d_out, int out_size, void* d_ws, size_t ws_size,
                              hipStream_t stream) {
    const int*   x     = (const int*)d_in[0];
    const int*   lengs = (const int*)d_in[1];
    const float* emb   = (const float*)d_in[2];
    const float* w_ih  = (const float*)d_in[3];
    const float* w_hh  = (const float*)d_in[4];
    const float* b_ih  = (const float*)d_in[5];
    const float* b_hh  = (const float*)d_in[6];
    const float* w_out = (const float*)d_in[7];
    const float* b_out = (const float*)d_in[8];
    float* out = (float*)d_out;

    float* emb_proj = (float*)d_ws;
    float* w_T      = emb_proj + (size_t)VOCAB * G4;
    float* w2       = w_T + (size_t)DW * G4;

    hipLaunchKernelGGL(prep_kernel, dim3((G4 * DW + DH * 208 + 255) / 256),
                       dim3(256), 0, stream, w_ih, w_hh, w_T, w2);
    hipLaunchKernelGGL(proj_kernel, dim3(VOCAB / 80), dim3(256), 0, stream,
                       emb, w_T, b_ih, b_hh, emb_proj);
    hipLaunchKernelGGL(lstm_kernel, dim3(BATCH), dim3(64), 0, stream,
                       x, lengs, emb_proj, w2, w_out, b_out, out);
}